// Round 3
// baseline (1657.944 us; speedup 1.0000x reference)
//
#include <hip/hip_runtime.h>
#include <hip/hip_bf16.h>
#include <hip/hip_cooperative_groups.h>
#include <type_traits>

namespace cg = cooperative_groups;

// R3: (a) replace per-layer grid.sync with per-batch sibling epoch-flag
// handshakes (grid.sync measured ~70us/layer of overhead in R2); (b) drop the
// ab LDS buffer (phase output goes directly to G), cutting LDS 152KB->78KB so
// 2 blocks/CU fit; (c) split each phase across 2 blocks -> 512 blocks, 4 per
// batch, 3 serial problems/wave, 4 waves/SIMD (2x latency hiding; R2 VALUBusy
// 48.5% at 2 waves/SIMD). Host queries occupancy: if 2 blocks/CU don't fit
// (VGPR creep), falls back to the 2-way 256-block variant (still flag-synced).
// One grid.sync at kernel start zero-initializes flags (d_ws is persistent).
#define BDIM 512
#define NBAT 128
#define SS   48
#define DD   8
#define HDIM 8
#define NL   8
#define NC   7
#define NWAV (BDIM/64)          // 8 waves/block
// LDS layout [i][d][j]: offset = i*RS + d*SS + j.  RS odd => both access
// orientations (lane-stride RS and lane-stride 1) are conflict-free.
#define RS   385
#define HSZ  (SS*RS)            // 18480 floats
#define PIX  (SS*SS)
#define GBAT (2*PIX*DD)         // per-batch exchange floats (row+col regions)
#define SMEM_FLOATS (HSZ + 264 + 784 + 8)
#define SMEM_BYTES  (SMEM_FLOATS*4)   // 78,144 B -> 2 blocks/CU
#define FLAGS_OFF ((size_t)NBAT * GBAT)   // float offset of flag array in d_ws

__device__ __forceinline__ float l2f(const float v)           { return v; }
__device__ __forceinline__ float l2f(const __hip_bfloat16 v)  { return __bfloat162float(v); }
__device__ __forceinline__ void  stf(float* p, float v)          { *p = v; }
__device__ __forceinline__ void  stf(__hip_bfloat16* p, float v) { *p = __float2bfloat16(v); }
__device__ __forceinline__ float rl(float v, int l) {
    return __int_as_float(__builtin_amdgcn_readlane(__float_as_int(v), l));
}

// Epoch flags: relaxed spins/stores; explicit __threadfence() provides the
// agent-scope release/acquire cache ops ONCE per gate (not per poll).
__device__ __forceinline__ void flag_post(unsigned* f, unsigned v) {
    __threadfence();                                   // release: drain + L2 wb
    __hip_atomic_store(f, v, __ATOMIC_RELAXED, __HIP_MEMORY_SCOPE_AGENT);
}
__device__ __forceinline__ void flag_wait(unsigned* f, unsigned v) {
    while (__hip_atomic_load(f, __ATOMIC_RELAXED, __HIP_MEMORY_SCOPE_AGENT) < v)
        __builtin_amdgcn_s_sleep(1);
}

// One axial-attention phase over LDS-resident h; writes its (pre-activation,
// bias-included) output DIRECTLY to the global exchange region gout in
// [prob][token][d] order (coalesced across tl for both phases; for the row
// phase this is the transposed [j][i][d] layout).
// COLPHASE=0: problems are columns j, tokens are rows i (row attention).
// COLPHASE=1: problems are rows i, tokens are cols j (col attention).
// wb layout: [0,64) Wq, [64,128) Wk, [128,192) Wv, [192,256) Wo, [256,264) bo.
template <int COLPHASE, int NPROB>
__device__ __attribute__((noinline))
void attn_phase(const float* __restrict__ hb, float* __restrict__ gout,
                const float* __restrict__ wb, int pbase, int wav, int lane, int tl)
{
    #pragma unroll 1
    for (int p = 0; p < NPROB/NWAV; ++p) {
        const int prob = pbase + wav + p*NWAV;
        const int base = COLPHASE ? (prob*RS + tl) : (tl*RS + prob);

        float ht[DD];
        #pragma unroll
        for (int d = 0; d < DD; ++d) ht[d] = hb[base + d*SS];

        // q/k/v projections; fold 0.5 (E^-0.5) * log2(e) into q for exp2.
        float q[HDIM], k[HDIM], v[HDIM];
        #pragma unroll
        for (int o = 0; o < HDIM; ++o) {
            float aq = 0.f, ak = 0.f, av = 0.f;
            #pragma unroll
            for (int d = 0; d < DD; ++d) {
                aq += ht[d] * wb[o*8 + d];
                ak += ht[d] * wb[64 + o*8 + d];
                av += ht[d] * wb[128 + o*8 + d];
            }
            q[o] = aq * 0.72134752044f;  // 0.5 * log2(e)
            k[o] = ak; v[o] = av;
        }

        float ov[HDIM];
        #pragma unroll
        for (int hh = 0; hh < 2; ++hh) {
            float dt[SS];
            #pragma unroll
            for (int j2 = 0; j2 < SS; ++j2) {
                float acc =  q[hh*4+0] * rl(k[hh*4+0], j2);
                acc       += q[hh*4+1] * rl(k[hh*4+1], j2);
                acc       += q[hh*4+2] * rl(k[hh*4+2], j2);
                acc       += q[hh*4+3] * rl(k[hh*4+3], j2);
                dt[j2] = acc;
            }
            float m = dt[0];
            #pragma unroll
            for (int j2 = 1; j2 < SS; ++j2) m = fmaxf(m, dt[j2]);
            float s = 0.f;
            #pragma unroll
            for (int j2 = 0; j2 < SS; ++j2) {
                float pv = exp2f(dt[j2] - m);
                dt[j2] = pv; s += pv;
            }
            float o0 = 0.f, o1 = 0.f, o2 = 0.f, o3 = 0.f;
            #pragma unroll
            for (int j2 = 0; j2 < SS; ++j2) {
                float pv = dt[j2];
                o0 += pv * rl(v[hh*4+0], j2);
                o1 += pv * rl(v[hh*4+1], j2);
                o2 += pv * rl(v[hh*4+2], j2);
                o3 += pv * rl(v[hh*4+3], j2);
            }
            float rs = 1.f / s;
            ov[hh*4+0] = o0*rs; ov[hh*4+1] = o1*rs;
            ov[hh*4+2] = o2*rs; ov[hh*4+3] = o3*rs;
        }

        if (lane < SS) {
            float o8[DD];
            #pragma unroll
            for (int d = 0; d < DD; ++d) {
                float acc = wb[256 + d];
                #pragma unroll
                for (int o2 = 0; o2 < HDIM; ++o2) acc += ov[o2] * wb[192 + d*8 + o2];
                o8[d] = acc;
            }
            float4* gp = reinterpret_cast<float4*>(gout + (size_t)(prob*SS + tl) * DD);
            gp[0] = make_float4(o8[0], o8[1], o8[2], o8[3]);
            gp[1] = make_float4(o8[4], o8[5], o8[6], o8[7]);
        }
    }
}

// NPART = blocks per batch (4: 2 halves x 2 axes; 2: one block per axis).
template <typename T, int NPART>
__global__ void __launch_bounds__(BDIM, 2)
axial_kernel(const void* xv, const void* enc_wv, const void* enc_bv,
             const void* pos_rowv, const void* pos_colv,
             const void* Wqv, const void* Wkv, const void* Wvv, const void* Wov,
             const void* bov, const void* cls_wv, const void* cls_bv,
             void* outv, void* wsv)
{
    // dtype sniff on x (robustness): low 16 bits of each dword are a plausible
    // bf16 exponent iff data is bf16-packed; random mantissa bits if fp32.
    const unsigned* xu = (const unsigned*)xv;
    int cnt = 0;
    #pragma unroll
    for (int t = 0; t < 32; ++t) {
        const unsigned w = xu[t];
        const int e = (w >> 7) & 0xff;
        cnt += (e > 100 && e < 150) ? 1 : 0;
    }
    const bool isbf = (cnt >= 20);
    constexpr bool wantbf = std::is_same<T, __hip_bfloat16>::value;
    if (isbf != wantbf) return;   // wrong-dtype instantiation: no-op

    cg::grid_group grid = cg::this_grid();

    const T* x       = (const T*)xv;
    const T* enc_w   = (const T*)enc_wv;
    const T* enc_b   = (const T*)enc_bv;
    const T* pos_row = (const T*)pos_rowv;
    const T* pos_col = (const T*)pos_colv;
    const T* Wq      = (const T*)Wqv;
    const T* Wk      = (const T*)Wkv;
    const T* Wv      = (const T*)Wvv;
    const T* Wo      = (const T*)Wov;
    const T* bo      = (const T*)bov;
    const T* cls_w   = (const T*)cls_wv;
    const T* cls_b   = (const T*)cls_bv;
    T*       out     = (T*)outv;
    float*   G       = (float*)wsv;                    // exchange: NBAT*GBAT floats
    unsigned* flags  = (unsigned*)(G + FLAGS_OFF);     // + NPART*NBAT epoch flags

    extern __shared__ float smem[];
    float* hb = smem;              // h image [HSZ]
    float* wb = hb + HSZ;          // layer weights (own axis) [264]
    float* eb = wb + 264;          // enc_w/enc_b/pos_row/pos_col [784]
    float* cb = eb + 784;          // classifier logits [8]

    const int bid   = blockIdx.x;
    const int batch = bid & (NBAT-1);
    const int part  = bid >> 7;                         // 0..NPART-1
    const int axis  = (NPART == 4) ? (part >> 1) : part;
    const int pbase = (NPART == 4) ? ((part & 1) * (SS/2)) : 0;
    constexpr int NPROB = (NPART == 4) ? (SS/2) : SS;
    const int tid   = threadIdx.x;
    const int lane  = tid & 63;
    const int wav   = tid >> 6;
    const int tl    = lane < SS ? lane : SS-1;

    float* Gb   = G + (size_t)batch * GBAT;
    float* Grow = Gb;               // row-attn output, TRANSPOSED [j][i][d]
    float* Gcol = Gb + PIX*DD;      // col-attn output, canonical [i][j][d]
    float* gout = axis ? Gcol : Grow;

    // zero epoch flags (d_ws persists across dispatches); one-time grid sync.
    if (tid == 0) flags[bid] = 0u;
    grid.sync();

    // stage encoder/pos params
    for (int f = tid; f < 784; f += BDIM) {
        float v;
        if (f < 8)        v = l2f(enc_w[f]);
        else if (f < 16)  v = l2f(enc_b[f-8]);
        else if (f < 400) v = l2f(pos_row[f-16]);
        else              v = l2f(pos_col[f-400]);
        eb[f] = v;
    }
    __syncthreads();

    // encoder: h = relu(x*enc_w + enc_b) + pos_row[i] + pos_col[j]
    // (all sibling blocks compute identical h)
    const T* xb = x + (size_t)batch * PIX;
    for (int p = tid; p < PIX; p += BDIM) {
        const int i = p / SS, j = p % SS;
        const float xv2 = l2f(xb[p]);
        #pragma unroll
        for (int d = 0; d < DD; ++d) {
            float hv = fmaxf(0.f, xv2*eb[d] + eb[8+d]) + eb[16 + i*8 + d] + eb[400 + j*8 + d];
            hb[i*RS + d*SS + j] = hv;
        }
    }

    // Flag protocol per layer l: WV(l)=2l+1 posted after own G write;
    // RV(l)=2l+2 posted after own read of siblings' layer-l data.
    // Pre-write gate waits siblings' RV(l-1)=2l (trivially true at l=0).
    #pragma unroll 1
    for (int l = 0; l < NL; ++l) {
        __syncthreads();                     // hb stable / prior wb reads done
        const int la = l*2 + axis;
        for (int f = tid; f < 264; f += BDIM) {
            float v;
            if (f < 64)       v = l2f(Wq[la*64 + f]);
            else if (f < 128) v = l2f(Wk[la*64 + f-64]);
            else if (f < 192) v = l2f(Wv[la*64 + f-128]);
            else if (f < 256) v = l2f(Wo[la*64 + f-192]);
            else              v = l2f(bo[la*8 + f-256]);
            wb[f] = v;
        }
        __syncthreads();

        // pre-write gate: siblings finished reading layer l-1 from our region
        if (tid == 0) {
            #pragma unroll
            for (int qp = 0; qp < NPART; ++qp)
                if (qp != part) flag_wait(&flags[batch + qp*NBAT], 2u*l);
        }
        __syncthreads();

        if (axis == 0) attn_phase<0, NPROB>(hb, gout, wb, pbase, wav, lane, tl);
        else           attn_phase<1, NPROB>(hb, gout, wb, pbase, wav, lane, tl);
        __syncthreads();                     // barrier drains the global stores

        if (tid == 0) {
            flag_post(&flags[bid], 2u*l + 1u);          // own quarter visible
            #pragma unroll
            for (int qp = 0; qp < NPART; ++qp)
                if (qp != part) flag_wait(&flags[batch + qp*NBAT], 2u*l + 1u);
            __threadfence();                 // acquire: invalidate stale caches
        }
        __syncthreads();

        if (l == NL-1 && part != 0) return;  // non-classifier blocks done

        // h-update pass A: col contribution, canonical (i,j) order (coalesced)
        for (int p = tid; p < PIX; p += BDIM) {
            const int i = p / SS, j = p % SS, base = i*RS + j;
            const float4* gp = reinterpret_cast<const float4*>(Gcol + (size_t)p * DD);
            const float4 g0 = gp[0], g1 = gp[1];
            hb[base     ] = g0.x;  hb[base+  SS] = g0.y;
            hb[base+2*SS] = g0.z;  hb[base+3*SS] = g0.w;
            hb[base+4*SS] = g1.x;  hb[base+5*SS] = g1.y;
            hb[base+6*SS] = g1.z;  hb[base+7*SS] = g1.w;
        }
        __syncthreads();
        // pass B: add row contribution (transposed (j,i) order -> coalesced
        // reads of Grow; LDS stride RS is conflict-free since RS odd), relu.
        for (int p2 = tid; p2 < PIX; p2 += BDIM) {
            const int j = p2 / SS, i = p2 % SS, base = i*RS + j;
            const float4* gp = reinterpret_cast<const float4*>(Grow + (size_t)p2 * DD);
            const float4 g0 = gp[0], g1 = gp[1];
            hb[base     ] = fmaxf(0.f, hb[base     ] + g0.x);
            hb[base+  SS] = fmaxf(0.f, hb[base+  SS] + g0.y);
            hb[base+2*SS] = fmaxf(0.f, hb[base+2*SS] + g0.z);
            hb[base+3*SS] = fmaxf(0.f, hb[base+3*SS] + g0.w);
            hb[base+4*SS] = fmaxf(0.f, hb[base+4*SS] + g1.x);
            hb[base+5*SS] = fmaxf(0.f, hb[base+5*SS] + g1.y);
            hb[base+6*SS] = fmaxf(0.f, hb[base+6*SS] + g1.z);
            hb[base+7*SS] = fmaxf(0.f, hb[base+7*SS] + g1.w);
        }
        if (l < NL-1) {
            __syncthreads();                 // all reads of G complete
            if (tid == 0) flag_post(&flags[bid], 2u*l + 2u);   // read-done
        }
    }
    __syncthreads();                         // only part==0 blocks reach here

    // max over d -> reuse eb region is too small; write into Gcol? use local:
    // classifier: logits[c] = sum_p max_d(h[p][d]) * cls_w[c][p] + cls_b[c]
    if (tid < NC) cb[tid] = l2f(cls_b[tid]);
    __syncthreads();

    float part_acc[NC] = {0.f,0.f,0.f,0.f,0.f,0.f,0.f};
    for (int p = tid; p < PIX; p += BDIM) {
        const int i = p / SS, j = p % SS;
        float mv = hb[i*RS + j];
        #pragma unroll
        for (int d = 1; d < DD; ++d) mv = fmaxf(mv, hb[i*RS + d*SS + j]);
        #pragma unroll
        for (int c = 0; c < NC; ++c) part_acc[c] += mv * l2f(cls_w[c*PIX + p]);
    }
    #pragma unroll
    for (int c = 0; c < NC; ++c) {
        #pragma unroll
        for (int off = 32; off > 0; off >>= 1) part_acc[c] += __shfl_down(part_acc[c], off, 64);
    }
    if (lane == 0) {
        #pragma unroll
        for (int c = 0; c < NC; ++c) atomicAdd(&cb[c], part_acc[c]);
    }
    __syncthreads();

    if (tid < NC) {
        float m = cb[0];
        #pragma unroll
        for (int c = 1; c < NC; ++c) m = fmaxf(m, cb[c]);
        float s = 0.f;
        #pragma unroll
        for (int c = 0; c < NC; ++c) s += exp2f((cb[c]-m) * 1.44269504089f);
        const float e = exp2f((cb[tid]-m) * 1.44269504089f);
        stf(&out[batch*NC + tid], e / s);
    }
}

extern "C" void kernel_launch(void* const* d_in, const int* in_sizes, int n_in,
                              void* d_out, int out_size, void* d_ws, size_t ws_size,
                              hipStream_t stream) {
    (void)in_sizes; (void)n_in; (void)ws_size; (void)out_size;
    hipFuncSetAttribute(reinterpret_cast<const void*>(&axial_kernel<float, 4>),
                        hipFuncAttributeMaxDynamicSharedMemorySize, SMEM_BYTES);
    hipFuncSetAttribute(reinterpret_cast<const void*>(&axial_kernel<__hip_bfloat16, 4>),
                        hipFuncAttributeMaxDynamicSharedMemorySize, SMEM_BYTES);
    hipFuncSetAttribute(reinterpret_cast<const void*>(&axial_kernel<float, 2>),
                        hipFuncAttributeMaxDynamicSharedMemorySize, SMEM_BYTES);
    hipFuncSetAttribute(reinterpret_cast<const void*>(&axial_kernel<__hip_bfloat16, 2>),
                        hipFuncAttributeMaxDynamicSharedMemorySize, SMEM_BYTES);

    void* ins[12];
    for (int i = 0; i < 12; ++i) ins[i] = d_in[i];
    void* args[14];
    for (int i = 0; i < 12; ++i) args[i] = &ins[i];
    args[12] = &d_out;
    args[13] = &d_ws;     // needs NBAT*GBAT*4 + NPART*NBAT*4 ~= 18.88 MB

    // 4-way split needs 2 blocks/CU (LDS 78KB, VGPR<=128). Verify via the
    // occupancy API (accounts actual VGPR/LDS); fall back to 2-way otherwise.
    int occ4f = 0, occ4b = 0;
    hipOccupancyMaxActiveBlocksPerMultiprocessor(
        &occ4f, reinterpret_cast<const void*>(&axial_kernel<float, 4>), BDIM, SMEM_BYTES);
    hipOccupancyMaxActiveBlocksPerMultiprocessor(
        &occ4b, reinterpret_cast<const void*>(&axial_kernel<__hip_bfloat16, 4>), BDIM, SMEM_BYTES);

    if (occ4f >= 2 && occ4b >= 2) {
        hipLaunchCooperativeKernel(reinterpret_cast<const void*>(&axial_kernel<float, 4>),
                                   dim3(4*NBAT), dim3(BDIM), args, (unsigned)SMEM_BYTES, stream);
        hipLaunchCooperativeKernel(reinterpret_cast<const void*>(&axial_kernel<__hip_bfloat16, 4>),
                                   dim3(4*NBAT), dim3(BDIM), args, (unsigned)SMEM_BYTES, stream);
    } else {
        hipLaunchCooperativeKernel(reinterpret_cast<const void*>(&axial_kernel<float, 2>),
                                   dim3(2*NBAT), dim3(BDIM), args, (unsigned)SMEM_BYTES, stream);
        hipLaunchCooperativeKernel(reinterpret_cast<const void*>(&axial_kernel<__hip_bfloat16, 2>),
                                   dim3(2*NBAT), dim3(BDIM), args, (unsigned)SMEM_BYTES, stream);
    }
}

// Round 4
// 1065.780 us; speedup vs baseline: 1.5556x; 1.5556x over previous
//
#include <hip/hip_runtime.h>
#include <hip/hip_bf16.h>
#include <type_traits>

// R4: (a) replace the readlane-broadcast inner loops with per-wave LDS k/v
// scratch read via ds_read_b128 same-address broadcast (free on CDNA): per
// token 8 VALU -> 4 VALU + 1 LGKM op, and k[8]/v[8] leave the register file
// (R3's 128-VGPR cap cliff -> ~90 regs, no spill). (b) keep the 2-way axis
// split + epoch-flag sync (grid.sync measured ~70us/layer in R2), flags now
// zeroed by hipMemsetAsync (no cg, no startup grid.sync). (c) proven-safe
// shape: 512 threads, __launch_bounds__(512,1) (R2: 124 VGPR no spill).
// Numerics: identical fma orders, serial sums; max chain -> max tree is
// bitwise-safe (fmax associative). LDS 102.7KB -> 1 block/CU; cooperative
// launch guarantees the co-residency the flag protocol requires.
#define BDIM 512
#define NBLK 256
#define NBAT 128
#define SS   48
#define DD   8
#define HDIM 8
#define NL   8
#define NC   7
#define NWAV (BDIM/64)          // 8 waves/block
#define PPW  (SS/NWAV)          // 6 serial problems per wave
// LDS layout [i][d][j]: offset = i*RS + d*SS + j.  RS odd => both access
// orientations (lane-stride RS and lane-stride 1) are conflict-free.
#define RS   385
#define HSZ  (SS*RS)            // 18480 floats
#define PIX  (SS*SS)
#define GBAT (2*PIX*DD)         // per-batch exchange floats (row+col regions)
#define KVV  384                // v offset within a wave's kv region (floats)
#define KVW  768                // per-wave kv floats: k[48][8] + v[48][8]
#define KVTOT (NWAV*KVW)        // 6144 floats
#define SMEM_FLOATS (HSZ + KVTOT + 264 + 784 + 8)
#define SMEM_BYTES  (SMEM_FLOATS*4)   // 102,720 B -> 1 block/CU
#define FLAGS_OFF ((size_t)NBAT * GBAT)   // float offset of flag array in d_ws

__device__ __forceinline__ float l2f(const float v)           { return v; }
__device__ __forceinline__ float l2f(const __hip_bfloat16 v)  { return __bfloat162float(v); }
__device__ __forceinline__ void  stf(float* p, float v)          { *p = v; }
__device__ __forceinline__ void  stf(__hip_bfloat16* p, float v) { *p = __float2bfloat16(v); }

// Epoch flags: relaxed spins/stores; explicit __threadfence() provides the
// agent-scope release/acquire cache ops ONCE per gate (not per poll).
__device__ __forceinline__ void flag_post(unsigned* f, unsigned v) {
    __threadfence();                                   // release: drain + L2 wb
    __hip_atomic_store(f, v, __ATOMIC_RELAXED, __HIP_MEMORY_SCOPE_AGENT);
}
__device__ __forceinline__ void flag_wait(unsigned* f, unsigned v) {
    while (__hip_atomic_load(f, __ATOMIC_RELAXED, __HIP_MEMORY_SCOPE_AGENT) < v)
        __builtin_amdgcn_s_sleep(1);
}

// One axial-attention phase over LDS-resident h; writes its (pre-activation,
// bias-included) output DIRECTLY to the global exchange region gout in
// [prob][token][d] order (coalesced for both phases; the row phase's region
// is therefore the transposed [j][i][d] layout).
// kvw: this wave's private LDS scratch (no cross-wave sync needed; the wave
// writes k/v then reads them back, compiler inserts the lgkmcnt waits).
// COLPHASE=0: problems are columns j, tokens are rows i (row attention).
// COLPHASE=1: problems are rows i, tokens are cols j (col attention).
// wb layout: [0,64) Wq, [64,128) Wk, [128,192) Wv, [192,256) Wo, [256,264) bo.
template <int COLPHASE>
__device__ __attribute__((noinline))
void attn_phase(const float* __restrict__ hb, float* __restrict__ kvw,
                float* __restrict__ gout, const float* __restrict__ wb,
                int wav, int lane, int tl)
{
    const float4* kv4 = reinterpret_cast<const float4*>(kvw);
    #pragma unroll 1
    for (int p = 0; p < PPW; ++p) {
        const int prob = wav + p*NWAV;
        const int base = COLPHASE ? (prob*RS + tl) : (tl*RS + prob);

        float ht[DD];
        #pragma unroll
        for (int d = 0; d < DD; ++d) ht[d] = hb[base + d*SS];

        // q/k/v projections; fold 0.5 (E^-0.5) * log2(e) into q for exp2.
        // k/v go straight to the wave's LDS scratch (short live ranges).
        float q[HDIM];
        {
            float kk[HDIM], vv[HDIM];
            #pragma unroll
            for (int o = 0; o < HDIM; ++o) {
                float aq = 0.f, ak = 0.f, av = 0.f;
                #pragma unroll
                for (int d = 0; d < DD; ++d) {
                    aq += ht[d] * wb[o*8 + d];
                    ak += ht[d] * wb[64 + o*8 + d];
                    av += ht[d] * wb[128 + o*8 + d];
                }
                q[o] = aq * 0.72134752044f;  // 0.5 * log2(e)
                kk[o] = ak; vv[o] = av;
            }
            if (lane < SS) {   // lanes 48-63 would duplicate token 47: skip
                float4* kp = reinterpret_cast<float4*>(kvw + tl*8);
                kp[0] = make_float4(kk[0], kk[1], kk[2], kk[3]);
                kp[1] = make_float4(kk[4], kk[5], kk[6], kk[7]);
                float4* vp = reinterpret_cast<float4*>(kvw + KVV + tl*8);
                vp[0] = make_float4(vv[0], vv[1], vv[2], vv[3]);
                vp[1] = make_float4(vv[4], vv[5], vv[6], vv[7]);
            }
        }

        float ov[HDIM];
        #pragma unroll
        for (int hh = 0; hh < 2; ++hh) {
            // dots: k[token][head] broadcast from LDS (same-address = free,
            // compile-time offset immediates, zero address VALU).
            float dt[SS];
            #pragma unroll
            for (int j2 = 0; j2 < SS; ++j2) {
                const float4 kk4 = kv4[j2*2 + hh];
                float acc =  q[hh*4+0] * kk4.x;
                acc       += q[hh*4+1] * kk4.y;
                acc       += q[hh*4+2] * kk4.z;
                acc       += q[hh*4+3] * kk4.w;
                dt[j2] = acc;
            }
            // max tree (fmax is exactly associative -> bitwise same as chain)
            float mt[24];
            #pragma unroll
            for (int t2 = 0; t2 < 24; ++t2) mt[t2] = fmaxf(dt[t2], dt[t2+24]);
            #pragma unroll
            for (int t2 = 0; t2 < 12; ++t2) mt[t2] = fmaxf(mt[t2], mt[t2+12]);
            #pragma unroll
            for (int t2 = 0; t2 < 6; ++t2)  mt[t2] = fmaxf(mt[t2], mt[t2+6]);
            #pragma unroll
            for (int t2 = 0; t2 < 3; ++t2)  mt[t2] = fmaxf(mt[t2], mt[t2+3]);
            const float m = fmaxf(fmaxf(mt[0], mt[1]), mt[2]);
            // exp + serial sum (kept serial: preserves exact rounding order)
            float s = 0.f;
            #pragma unroll
            for (int j2 = 0; j2 < SS; ++j2) {
                float pv = exp2f(dt[j2] - m);
                dt[j2] = pv; s += pv;
            }
            // PV: v broadcast from LDS, 4 independent fma chains
            float o0 = 0.f, o1 = 0.f, o2 = 0.f, o3 = 0.f;
            #pragma unroll
            for (int j2 = 0; j2 < SS; ++j2) {
                const float4 vv4 = kv4[KVV/4 + j2*2 + hh];
                const float pv = dt[j2];
                o0 += pv * vv4.x;
                o1 += pv * vv4.y;
                o2 += pv * vv4.z;
                o3 += pv * vv4.w;
            }
            float rs = 1.f / s;
            ov[hh*4+0] = o0*rs; ov[hh*4+1] = o1*rs;
            ov[hh*4+2] = o2*rs; ov[hh*4+3] = o3*rs;
        }

        if (lane < SS) {
            float o8[DD];
            #pragma unroll
            for (int d = 0; d < DD; ++d) {
                float acc = wb[256 + d];
                #pragma unroll
                for (int o2 = 0; o2 < HDIM; ++o2) acc += ov[o2] * wb[192 + d*8 + o2];
                o8[d] = acc;
            }
            float4* gp = reinterpret_cast<float4*>(gout + (size_t)(prob*SS + tl) * DD);
            gp[0] = make_float4(o8[0], o8[1], o8[2], o8[3]);
            gp[1] = make_float4(o8[4], o8[5], o8[6], o8[7]);
        }
    }
}

template <typename T>
__global__ void __launch_bounds__(BDIM, 1)   // proven no-spill shape (R2: 124 VGPR)
axial_kernel(const void* xv, const void* enc_wv, const void* enc_bv,
             const void* pos_rowv, const void* pos_colv,
             const void* Wqv, const void* Wkv, const void* Wvv, const void* Wov,
             const void* bov, const void* cls_wv, const void* cls_bv,
             void* outv, void* wsv)
{
    // dtype sniff on x (robustness): low 16 bits of each dword are a plausible
    // bf16 exponent iff data is bf16-packed; random mantissa bits if fp32.
    const unsigned* xu = (const unsigned*)xv;
    int cnt = 0;
    #pragma unroll
    for (int t = 0; t < 32; ++t) {
        const unsigned w = xu[t];
        const int e = (w >> 7) & 0xff;
        cnt += (e > 100 && e < 150) ? 1 : 0;
    }
    const bool isbf = (cnt >= 20);
    constexpr bool wantbf = std::is_same<T, __hip_bfloat16>::value;
    if (isbf != wantbf) return;   // wrong-dtype instantiation: no-op

    const T* x       = (const T*)xv;
    const T* enc_w   = (const T*)enc_wv;
    const T* enc_b   = (const T*)enc_bv;
    const T* pos_row = (const T*)pos_rowv;
    const T* pos_col = (const T*)pos_colv;
    const T* Wq      = (const T*)Wqv;
    const T* Wk      = (const T*)Wkv;
    const T* Wv      = (const T*)Wvv;
    const T* Wo      = (const T*)Wov;
    const T* bo      = (const T*)bov;
    const T* cls_w   = (const T*)cls_wv;
    const T* cls_b   = (const T*)cls_bv;
    T*       out     = (T*)outv;
    float*   G       = (float*)wsv;                    // exchange: NBAT*GBAT floats
    unsigned* flags  = (unsigned*)(G + FLAGS_OFF);     // + NBLK epoch flags (host-zeroed)

    extern __shared__ float smem[];
    float* hb = smem;              // h image [HSZ]
    float* kv = hb + HSZ;          // per-wave k/v scratch [KVTOT]
    float* wb = kv + KVTOT;        // layer weights (own axis) [264]
    float* eb = wb + 264;          // enc_w/enc_b/pos_row/pos_col [784]
    float* cb = eb + 784;          // classifier logits [8]

    const int bid   = blockIdx.x;
    const int batch = bid & (NBAT-1);
    const int axis  = bid >> 7;            // 0: row attention, 1: col attention
    const int tid   = threadIdx.x;
    const int lane  = tid & 63;
    const int wav   = tid >> 6;
    const int tl    = lane < SS ? lane : SS-1;

    float* Gb   = G + (size_t)batch * GBAT;
    float* Grow = Gb;               // row-attn output, TRANSPOSED [j][i][d]
    float* Gcol = Gb + PIX*DD;      // col-attn output, canonical [i][j][d]
    float* gout = axis ? Gcol : Grow;
    float* kvw  = kv + wav*KVW;     // this wave's private scratch

    // stage encoder/pos params
    for (int f = tid; f < 784; f += BDIM) {
        float v;
        if (f < 8)        v = l2f(enc_w[f]);
        else if (f < 16)  v = l2f(enc_b[f-8]);
        else if (f < 400) v = l2f(pos_row[f-16]);
        else              v = l2f(pos_col[f-400]);
        eb[f] = v;
    }
    __syncthreads();

    // encoder: h = relu(x*enc_w + enc_b) + pos_row[i] + pos_col[j]
    // (both sibling blocks compute identical h)
    const T* xb = x + (size_t)batch * PIX;
    for (int p = tid; p < PIX; p += BDIM) {
        const int i = p / SS, j = p % SS;
        const float xv2 = l2f(xb[p]);
        #pragma unroll
        for (int d = 0; d < DD; ++d) {
            float hv = fmaxf(0.f, xv2*eb[d] + eb[8+d]) + eb[16 + i*8 + d] + eb[400 + j*8 + d];
            hb[i*RS + d*SS + j] = hv;
        }
    }

    // Flag protocol per layer l: WV(l)=2l+1 posted after own G write;
    // RV(l)=2l+2 posted after own read of sibling's layer-l data.
    // Pre-write gate waits sibling's RV(l-1)=2l (trivially true at l=0).
    unsigned* sibf = &flags[bid ^ NBAT];
    #pragma unroll 1
    for (int l = 0; l < NL; ++l) {
        __syncthreads();                     // hb stable / prior wb reads done
        const int la = l*2 + axis;
        for (int f = tid; f < 264; f += BDIM) {
            float v;
            if (f < 64)       v = l2f(Wq[la*64 + f]);
            else if (f < 128) v = l2f(Wk[la*64 + f-64]);
            else if (f < 192) v = l2f(Wv[la*64 + f-128]);
            else if (f < 256) v = l2f(Wo[la*64 + f-192]);
            else              v = l2f(bo[la*8 + f-256]);
            wb[f] = v;
        }
        __syncthreads();

        // pre-write gate: sibling finished reading layer l-1 from our region
        if (tid == 0) flag_wait(sibf, 2u*l);
        __syncthreads();

        if (axis == 0) attn_phase<0>(hb, kvw, gout, wb, wav, lane, tl);
        else           attn_phase<1>(hb, kvw, gout, wb, wav, lane, tl);
        __syncthreads();                     // barrier drains the global stores

        if (tid == 0) {
            flag_post(&flags[bid], 2u*l + 1u);   // own half visible
            flag_wait(sibf, 2u*l + 1u);
            __threadfence();                 // acquire: invalidate stale caches
        }
        __syncthreads();

        if (l == NL-1 && axis != 0) return;  // col block done after last gate

        // h-update pass A: col contribution, canonical (i,j) order (coalesced)
        for (int p = tid; p < PIX; p += BDIM) {
            const int i = p / SS, j = p % SS, base = i*RS + j;
            const float4* gp = reinterpret_cast<const float4*>(Gcol + (size_t)p * DD);
            const float4 g0 = gp[0], g1 = gp[1];
            hb[base     ] = g0.x;  hb[base+  SS] = g0.y;
            hb[base+2*SS] = g0.z;  hb[base+3*SS] = g0.w;
            hb[base+4*SS] = g1.x;  hb[base+5*SS] = g1.y;
            hb[base+6*SS] = g1.z;  hb[base+7*SS] = g1.w;
        }
        __syncthreads();
        // pass B: add row contribution (transposed (j,i) order -> coalesced
        // reads of Grow; LDS stride RS conflict-free since RS%32==1), relu.
        // fp32 add is commutative -> both siblings get bitwise-identical h.
        for (int p2 = tid; p2 < PIX; p2 += BDIM) {
            const int j = p2 / SS, i = p2 % SS, base = i*RS + j;
            const float4* gp = reinterpret_cast<const float4*>(Grow + (size_t)p2 * DD);
            const float4 g0 = gp[0], g1 = gp[1];
            hb[base     ] = fmaxf(0.f, hb[base     ] + g0.x);
            hb[base+  SS] = fmaxf(0.f, hb[base+  SS] + g0.y);
            hb[base+2*SS] = fmaxf(0.f, hb[base+2*SS] + g0.z);
            hb[base+3*SS] = fmaxf(0.f, hb[base+3*SS] + g0.w);
            hb[base+4*SS] = fmaxf(0.f, hb[base+4*SS] + g1.x);
            hb[base+5*SS] = fmaxf(0.f, hb[base+5*SS] + g1.y);
            hb[base+6*SS] = fmaxf(0.f, hb[base+6*SS] + g1.z);
            hb[base+7*SS] = fmaxf(0.f, hb[base+7*SS] + g1.w);
        }
        if (l < NL-1) {
            __syncthreads();                 // all reads of G complete
            if (tid == 0) flag_post(&flags[bid], 2u*l + 2u);   // read-done
        }
    }
    __syncthreads();                         // only axis==0 blocks reach here

    // classifier: logits[c] = sum_p max_d(h[p][d]) * cls_w[c][p] + cls_b[c]
    if (tid < NC) cb[tid] = l2f(cls_b[tid]);
    __syncthreads();

    float part_acc[NC] = {0.f,0.f,0.f,0.f,0.f,0.f,0.f};
    for (int p = tid; p < PIX; p += BDIM) {
        const int i = p / SS, j = p % SS;
        float mv = hb[i*RS + j];
        #pragma unroll
        for (int d = 1; d < DD; ++d) mv = fmaxf(mv, hb[i*RS + d*SS + j]);
        #pragma unroll
        for (int c = 0; c < NC; ++c) part_acc[c] += mv * l2f(cls_w[c*PIX + p]);
    }
    #pragma unroll
    for (int c = 0; c < NC; ++c) {
        #pragma unroll
        for (int off = 32; off > 0; off >>= 1) part_acc[c] += __shfl_down(part_acc[c], off, 64);
    }
    if (lane == 0) {
        #pragma unroll
        for (int c = 0; c < NC; ++c) atomicAdd(&cb[c], part_acc[c]);
    }
    __syncthreads();

    if (tid < NC) {
        float m = cb[0];
        #pragma unroll
        for (int c = 1; c < NC; ++c) m = fmaxf(m, cb[c]);
        float s = 0.f;
        #pragma unroll
        for (int c = 0; c < NC; ++c) s += exp2f((cb[c]-m) * 1.44269504089f);
        const float e = exp2f((cb[tid]-m) * 1.44269504089f);
        stf(&out[batch*NC + tid], e / s);
    }
}

extern "C" void kernel_launch(void* const* d_in, const int* in_sizes, int n_in,
                              void* d_out, int out_size, void* d_ws, size_t ws_size,
                              hipStream_t stream) {
    (void)in_sizes; (void)n_in; (void)ws_size; (void)out_size;
    hipFuncSetAttribute(reinterpret_cast<const void*>(&axial_kernel<float>),
                        hipFuncAttributeMaxDynamicSharedMemorySize, SMEM_BYTES);
    hipFuncSetAttribute(reinterpret_cast<const void*>(&axial_kernel<__hip_bfloat16>),
                        hipFuncAttributeMaxDynamicSharedMemorySize, SMEM_BYTES);

    // zero the epoch flags (stream-ordered, graph-capture-safe like MemcpyAsync)
    hipMemsetAsync((char*)d_ws + FLAGS_OFF*4, 0, NBLK*sizeof(unsigned), stream);

    void* ins[12];
    for (int i = 0; i < 12; ++i) ins[i] = d_in[i];
    void* args[14];
    for (int i = 0; i < 12; ++i) args[i] = &ins[i];
    args[12] = &d_out;
    args[13] = &d_ws;     // needs NBAT*GBAT*4 + NBLK*4 ~= 18.88 MB

    // cooperative launch: guarantees all 256 blocks co-resident (flag protocol)
    hipLaunchCooperativeKernel(reinterpret_cast<const void*>(&axial_kernel<float>),
                               dim3(NBLK), dim3(BDIM), args, (unsigned)SMEM_BYTES, stream);
    hipLaunchCooperativeKernel(reinterpret_cast<const void*>(&axial_kernel<__hip_bfloat16>),
                               dim3(NBLK), dim3(BDIM), args, (unsigned)SMEM_BYTES, stream);
}

// Round 5
// 1025.826 us; speedup vs baseline: 1.6162x; 1.0389x over previous
//
#include <hip/hip_runtime.h>
#include <hip/hip_bf16.h>
#include <type_traits>

// R5: eliminate the LDS h image entirely. Each h element is read exactly once
// per layer per block, so the phase reads relu(col+row) DIRECTLY from the
// double-buffered global exchange (bitwise identical: fp32 add commutative,
// same fmax), and writes its output to the other parity. This deletes the
// h-update passes (+3 barriers/layer), cuts sync to 1 post + <=2 waits per
// layer (double-buffer => WV(l-1) implies read-safety; own-orientation region
// is self-written so only opposite-axis siblings gate), and shrinks LDS
// 102.7KB -> 28.8KB so 2 blocks/CU fit => 4-way split (512 blocks, 3
// problems/wave, 16 waves/CU) with gate stalls overlapped by the co-resident
// block. h0 is written redundantly by all siblings in BOTH layouts (benign
// identical-value race; layer-0 reads single-region, no relu).
// Fallbacks: occupancy<2 => fused NPART=2 (256 blocks); ws too small => R4
// single-buffer kernel verbatim.
#define BDIM 512
#define NBAT 128
#define SS   48
#define DD   8
#define HDIM 8
#define NL   8
#define NC   7
#define NWAV 8
#define PIX  (SS*SS)
#define RGN  (PIX*DD)            // one region: 18432 floats
#define GBAT (2*RGN)             // row+col regions per batch
#define BUFSZ ((size_t)NBAT*GBAT)      // one parity buffer (floats)
#define KVV  384
#define KVW  768
#define KVTOT (NWAV*KVW)
// fused kernel LDS
#define SMEMF_FLOATS (KVTOT + 264 + 784 + 8)
#define SMEMF_BYTES  (SMEMF_FLOATS*4)        // 28,800 B
#define FLAGS_OFF_F  ((size_t)2*BUFSZ)       // float offset of flags (fused)
// single-buffer fallback (R4) LDS
#define RS   385
#define HSZ  (SS*RS)
#define PPW  (SS/NWAV)
#define SMEMSB_FLOATS (HSZ + KVTOT + 264 + 784 + 8)
#define SMEMSB_BYTES  (SMEMSB_FLOATS*4)      // 102,720 B
#define FLAGS_OFF_SB  (BUFSZ)

__device__ __forceinline__ float l2f(const float v)           { return v; }
__device__ __forceinline__ float l2f(const __hip_bfloat16 v)  { return __bfloat162float(v); }
__device__ __forceinline__ void  stf(float* p, float v)          { *p = v; }
__device__ __forceinline__ void  stf(__hip_bfloat16* p, float v) { *p = __float2bfloat16(v); }

__device__ __forceinline__ void flag_post(unsigned* f, unsigned v) {
    __threadfence();                                   // release: drain + L2 wb
    __hip_atomic_store(f, v, __ATOMIC_RELAXED, __HIP_MEMORY_SCOPE_AGENT);
}
__device__ __forceinline__ void flag_wait(unsigned* f, unsigned v) {
    while (__hip_atomic_load(f, __ATOMIC_RELAXED, __HIP_MEMORY_SCOPE_AGENT) < v)
        __builtin_amdgcn_s_sleep(1);
}

// ---------------------------------------------------------------------------
// Fused phase: input read straight from exchange buffers, output straight to
// the other parity. "own" region matches this phase's orientation (self-written
// last layer, index (prob*SS+tl): coalesced); "oth" is the opposite region
// (index (tl*SS+prob): 32B-scattered, L2-absorbed). FIRST=1: layer 0, read h0
// as-is from own-layout copy (no relu, no add).
template <int NPROB, int FIRST>
__device__ __attribute__((noinline))
void attn_phase_f(const float4* __restrict__ gown, const float4* __restrict__ goth,
                  float4* __restrict__ gout, float* __restrict__ kvw,
                  const float* __restrict__ wb, int pbase, int wav, int lane, int tl)
{
    const float4* kv4 = reinterpret_cast<const float4*>(kvw);
    #pragma unroll 1
    for (int p = 0; p < NPROB/NWAV; ++p) {
        const int prob = pbase + wav + p*NWAV;
        const int aown = (prob*SS + tl)*2;

        float ht[DD];
        {
            const float4 o0 = gown[aown], o1 = gown[aown+1];
            if (FIRST) {
                ht[0]=o0.x; ht[1]=o0.y; ht[2]=o0.z; ht[3]=o0.w;
                ht[4]=o1.x; ht[5]=o1.y; ht[6]=o1.z; ht[7]=o1.w;
            } else {
                const int aoth = (tl*SS + prob)*2;
                const float4 t0 = goth[aoth], t1 = goth[aoth+1];
                ht[0]=fmaxf(0.f,o0.x+t0.x); ht[1]=fmaxf(0.f,o0.y+t0.y);
                ht[2]=fmaxf(0.f,o0.z+t0.z); ht[3]=fmaxf(0.f,o0.w+t0.w);
                ht[4]=fmaxf(0.f,o1.x+t1.x); ht[5]=fmaxf(0.f,o1.y+t1.y);
                ht[6]=fmaxf(0.f,o1.z+t1.z); ht[7]=fmaxf(0.f,o1.w+t1.w);
            }
        }

        // q/k/v projections; fold 0.5 (E^-0.5) * log2(e) into q for exp2.
        float q[HDIM];
        {
            float kk[HDIM], vv[HDIM];
            #pragma unroll
            for (int o = 0; o < HDIM; ++o) {
                float aq = 0.f, ak = 0.f, av = 0.f;
                #pragma unroll
                for (int d = 0; d < DD; ++d) {
                    aq += ht[d] * wb[o*8 + d];
                    ak += ht[d] * wb[64 + o*8 + d];
                    av += ht[d] * wb[128 + o*8 + d];
                }
                q[o] = aq * 0.72134752044f;  // 0.5 * log2(e)
                kk[o] = ak; vv[o] = av;
            }
            if (lane < SS) {   // lanes 48-63 would duplicate token 47: skip
                float4* kp = reinterpret_cast<float4*>(kvw + tl*8);
                kp[0] = make_float4(kk[0], kk[1], kk[2], kk[3]);
                kp[1] = make_float4(kk[4], kk[5], kk[6], kk[7]);
                float4* vp = reinterpret_cast<float4*>(kvw + KVV + tl*8);
                vp[0] = make_float4(vv[0], vv[1], vv[2], vv[3]);
                vp[1] = make_float4(vv[4], vv[5], vv[6], vv[7]);
            }
        }

        float ov[HDIM];
        #pragma unroll
        for (int hh = 0; hh < 2; ++hh) {
            float dt[SS];
            #pragma unroll
            for (int j2 = 0; j2 < SS; ++j2) {
                const float4 kk4 = kv4[j2*2 + hh];       // LDS same-addr broadcast
                float acc =  q[hh*4+0] * kk4.x;
                acc       += q[hh*4+1] * kk4.y;
                acc       += q[hh*4+2] * kk4.z;
                acc       += q[hh*4+3] * kk4.w;
                dt[j2] = acc;
            }
            // max tree (fmax exactly associative -> bitwise same as chain)
            float mt[24];
            #pragma unroll
            for (int t2 = 0; t2 < 24; ++t2) mt[t2] = fmaxf(dt[t2], dt[t2+24]);
            #pragma unroll
            for (int t2 = 0; t2 < 12; ++t2) mt[t2] = fmaxf(mt[t2], mt[t2+12]);
            #pragma unroll
            for (int t2 = 0; t2 < 6; ++t2)  mt[t2] = fmaxf(mt[t2], mt[t2+6]);
            #pragma unroll
            for (int t2 = 0; t2 < 3; ++t2)  mt[t2] = fmaxf(mt[t2], mt[t2+3]);
            const float m = fmaxf(fmaxf(mt[0], mt[1]), mt[2]);
            float s = 0.f;
            #pragma unroll
            for (int j2 = 0; j2 < SS; ++j2) {
                float pv = exp2f(dt[j2] - m);
                dt[j2] = pv; s += pv;
            }
            float o0 = 0.f, o1 = 0.f, o2 = 0.f, o3 = 0.f;
            #pragma unroll
            for (int j2 = 0; j2 < SS; ++j2) {
                const float4 vv4 = kv4[KVV/4 + j2*2 + hh];
                const float pv = dt[j2];
                o0 += pv * vv4.x;
                o1 += pv * vv4.y;
                o2 += pv * vv4.z;
                o3 += pv * vv4.w;
            }
            float rs = 1.f / s;
            ov[hh*4+0] = o0*rs; ov[hh*4+1] = o1*rs;
            ov[hh*4+2] = o2*rs; ov[hh*4+3] = o3*rs;
        }

        if (lane < SS) {
            float o8[DD];
            #pragma unroll
            for (int d = 0; d < DD; ++d) {
                float acc = wb[256 + d];
                #pragma unroll
                for (int o2 = 0; o2 < HDIM; ++o2) acc += ov[o2] * wb[192 + d*8 + o2];
                o8[d] = acc;
            }
            gout[aown]   = make_float4(o8[0], o8[1], o8[2], o8[3]);
            gout[aown+1] = make_float4(o8[4], o8[5], o8[6], o8[7]);
        }
    }
}

// NPART=4: 512 blocks (2 halves x 2 axes per batch); NPART=2: 256 blocks.
template <typename T, int NPART>
__global__ void __launch_bounds__(BDIM, 1)
axial_f(const void* xv, const void* enc_wv, const void* enc_bv,
        const void* pos_rowv, const void* pos_colv,
        const void* Wqv, const void* Wkv, const void* Wvv, const void* Wov,
        const void* bov, const void* cls_wv, const void* cls_bv,
        void* outv, void* wsv)
{
    const unsigned* xu = (const unsigned*)xv;
    int cnt = 0;
    #pragma unroll
    for (int t = 0; t < 32; ++t) {
        const unsigned w = xu[t];
        const int e = (w >> 7) & 0xff;
        cnt += (e > 100 && e < 150) ? 1 : 0;
    }
    const bool isbf = (cnt >= 20);
    constexpr bool wantbf = std::is_same<T, __hip_bfloat16>::value;
    if (isbf != wantbf) return;

    const T* x       = (const T*)xv;
    const T* enc_w   = (const T*)enc_wv;
    const T* enc_b   = (const T*)enc_bv;
    const T* pos_row = (const T*)pos_rowv;
    const T* pos_col = (const T*)pos_colv;
    const T* Wq      = (const T*)Wqv;
    const T* Wk      = (const T*)Wkv;
    const T* Wv      = (const T*)Wvv;
    const T* Wo      = (const T*)Wov;
    const T* bo      = (const T*)bov;
    const T* cls_w   = (const T*)cls_wv;
    const T* cls_b   = (const T*)cls_bv;
    T*       out     = (T*)outv;
    float*   G       = (float*)wsv;
    unsigned* flags  = (unsigned*)(G + FLAGS_OFF_F);

    extern __shared__ float smem[];
    float* kv = smem;              // per-wave k/v scratch [KVTOT]
    float* wb = kv + KVTOT;        // layer weights (own axis) [264]
    float* eb = wb + 264;          // enc params [784]
    float* cb = eb + 784;          // classifier logits [8]

    const int bid   = blockIdx.x;
    const int batch = bid & (NBAT-1);
    const int part  = bid >> 7;                         // 0..NPART-1
    const int axis  = (NPART == 4) ? (part >> 1) : part;
    const int pbase = (NPART == 4) ? ((part & 1) * (SS/2)) : 0;
    constexpr int NPROB = (NPART == 4) ? (SS/2) : SS;
    const int tid   = threadIdx.x;
    const int lane  = tid & 63;
    const int wav   = tid >> 6;
    const int tl    = lane < SS ? lane : SS-1;
    float* kvw = kv + wav*KVW;

    float* b0 = G + (size_t)batch*GBAT;                 // parity-0 buffer
    float* b1 = G + BUFSZ + (size_t)batch*GBAT;         // parity-1 buffer
    float4* row0 = (float4*)b0;  float4* col0 = (float4*)(b0 + RGN);
    float4* row1 = (float4*)b1;  float4* col1 = (float4*)(b1 + RGN);

    // stage encoder/pos params
    for (int f = tid; f < 784; f += BDIM) {
        float v;
        if (f < 8)        v = l2f(enc_w[f]);
        else if (f < 16)  v = l2f(enc_b[f-8]);
        else if (f < 400) v = l2f(pos_row[f-16]);
        else              v = l2f(pos_col[f-400]);
        eb[f] = v;
    }
    __syncthreads();

    // encoder: h0 = relu(x*enc_w + enc_b) + pos_row[i] + pos_col[j].
    // Every sibling writes the FULL image in BOTH layouts (identical values ->
    // benign race; own copy guarantees own-visibility, so no startup gate).
    const T* xb = x + (size_t)batch * PIX;
    for (int p = tid; p < PIX; p += BDIM) {
        const int i = p / SS, j = p % SS;
        const float xv2 = l2f(xb[p]);
        float hv[DD];
        #pragma unroll
        for (int d = 0; d < DD; ++d)
            hv[d] = fmaxf(0.f, xv2*eb[d] + eb[8+d]) + eb[16 + i*8 + d] + eb[400 + j*8 + d];
        const float4 a = make_float4(hv[0], hv[1], hv[2], hv[3]);
        const float4 b = make_float4(hv[4], hv[5], hv[6], hv[7]);
        col0[p*2] = a;              col0[p*2+1] = b;            // [i][j][d]
        row0[(j*SS+i)*2] = a;       row0[(j*SS+i)*2+1] = b;     // [j][i][d]
    }

    // Layer l: reads parity l&1, writes parity (l+1)&1. WV(l)=l+1 posted after
    // the phase. Gate before layer l>0: opposite-axis siblings' WV(l-1) (own
    // region is self-written; double-buffer makes WV imply read-safety).
    #pragma unroll 1
    for (int l = 0; l < NL; ++l) {
        __syncthreads();                     // prior phase wb reads / encoder done
        if (tid == 0 && l > 0) {
            if (NPART == 4) {
                const int ob = axis ? 0 : 2;
                flag_wait(&flags[batch + ob*NBAT],     (unsigned)l);
                flag_wait(&flags[batch + (ob+1)*NBAT], (unsigned)l);
            } else {
                flag_wait(&flags[batch + (1-axis)*NBAT], (unsigned)l);
            }
            __threadfence();                 // acquire: invalidate stale caches
        }
        const int la = l*2 + axis;
        for (int f = tid; f < 264; f += BDIM) {
            float v;
            if (f < 64)       v = l2f(Wq[la*64 + f]);
            else if (f < 128) v = l2f(Wk[la*64 + f-64]);
            else if (f < 192) v = l2f(Wv[la*64 + f-128]);
            else if (f < 256) v = l2f(Wo[la*64 + f-192]);
            else              v = l2f(bo[la*8 + f-256]);
            wb[f] = v;
        }
        __syncthreads();                     // gate released + wb visible

        const int par = l & 1;
        float4* rin  = par ? row1 : row0;  float4* cin  = par ? col1 : col0;
        float4* rout = par ? row0 : row1;  float4* cout = par ? col0 : col1;
        const float4* own = axis ? (const float4*)cin : (const float4*)rin;
        const float4* oth = axis ? (const float4*)rin : (const float4*)cin;
        float4* gout = axis ? cout : rout;

        if (l == 0) attn_phase_f<NPROB,1>(own, oth, gout, kvw, wb, pbase, wav, lane, tl);
        else        attn_phase_f<NPROB,0>(own, oth, gout, kvw, wb, pbase, wav, lane, tl);
        __syncthreads();                     // drains each wave's global stores

        if (tid == 0) flag_post(&flags[bid], (unsigned)(l + 1));
    }

    if (part != 0) return;

    // classifier (part 0 of each batch): final h lives in parity 0 (NL even).
    if (tid == 0) {
        #pragma unroll
        for (int qp = 1; qp < NPART; ++qp)
            flag_wait(&flags[batch + qp*NBAT], (unsigned)NL);
        __threadfence();
    }
    if (tid < NC) cb[tid] = l2f(cls_b[tid]);
    __syncthreads();

    float pacc[NC] = {0.f,0.f,0.f,0.f,0.f,0.f,0.f};
    for (int p = tid; p < PIX; p += BDIM) {
        const int i = p / SS, j = p % SS;
        const float4 c0 = col0[p*2], c1 = col0[p*2+1];
        const float4 r0 = row0[(j*SS+i)*2], r1 = row0[(j*SS+i)*2+1];
        float mv =            fmaxf(0.f, c0.x + r0.x);
        mv = fmaxf(mv,        fmaxf(0.f, c0.y + r0.y));
        mv = fmaxf(mv,        fmaxf(0.f, c0.z + r0.z));
        mv = fmaxf(mv,        fmaxf(0.f, c0.w + r0.w));
        mv = fmaxf(mv,        fmaxf(0.f, c1.x + r1.x));
        mv = fmaxf(mv,        fmaxf(0.f, c1.y + r1.y));
        mv = fmaxf(mv,        fmaxf(0.f, c1.z + r1.z));
        mv = fmaxf(mv,        fmaxf(0.f, c1.w + r1.w));
        #pragma unroll
        for (int c = 0; c < NC; ++c) pacc[c] += mv * l2f(cls_w[c*PIX + p]);
    }
    #pragma unroll
    for (int c = 0; c < NC; ++c) {
        #pragma unroll
        for (int off = 32; off > 0; off >>= 1) pacc[c] += __shfl_down(pacc[c], off, 64);
    }
    if (lane == 0) {
        #pragma unroll
        for (int c = 0; c < NC; ++c) atomicAdd(&cb[c], pacc[c]);
    }
    __syncthreads();

    if (tid < NC) {
        float m = cb[0];
        #pragma unroll
        for (int c = 1; c < NC; ++c) m = fmaxf(m, cb[c]);
        float s = 0.f;
        #pragma unroll
        for (int c = 0; c < NC; ++c) s += exp2f((cb[c]-m) * 1.44269504089f);
        const float e = exp2f((cb[tid]-m) * 1.44269504089f);
        stf(&out[batch*NC + tid], e / s);
    }
}

// ---------------------------------------------------------------------------
// R4 single-buffer kernel, kept verbatim as the ws_size fallback.
template <int COLPHASE>
__device__ __attribute__((noinline))
void attn_phase_sb(const float* __restrict__ hb, float* __restrict__ kvw,
                   float* __restrict__ gout, const float* __restrict__ wb,
                   int wav, int lane, int tl)
{
    const float4* kv4 = reinterpret_cast<const float4*>(kvw);
    #pragma unroll 1
    for (int p = 0; p < PPW; ++p) {
        const int prob = wav + p*NWAV;
        const int base = COLPHASE ? (prob*RS + tl) : (tl*RS + prob);
        float ht[DD];
        #pragma unroll
        for (int d = 0; d < DD; ++d) ht[d] = hb[base + d*SS];
        float q[HDIM];
        {
            float kk[HDIM], vv[HDIM];
            #pragma unroll
            for (int o = 0; o < HDIM; ++o) {
                float aq = 0.f, ak = 0.f, av = 0.f;
                #pragma unroll
                for (int d = 0; d < DD; ++d) {
                    aq += ht[d] * wb[o*8 + d];
                    ak += ht[d] * wb[64 + o*8 + d];
                    av += ht[d] * wb[128 + o*8 + d];
                }
                q[o] = aq * 0.72134752044f;
                kk[o] = ak; vv[o] = av;
            }
            if (lane < SS) {
                float4* kp = reinterpret_cast<float4*>(kvw + tl*8);
                kp[0] = make_float4(kk[0], kk[1], kk[2], kk[3]);
                kp[1] = make_float4(kk[4], kk[5], kk[6], kk[7]);
                float4* vp = reinterpret_cast<float4*>(kvw + KVV + tl*8);
                vp[0] = make_float4(vv[0], vv[1], vv[2], vv[3]);
                vp[1] = make_float4(vv[4], vv[5], vv[6], vv[7]);
            }
        }
        float ov[HDIM];
        #pragma unroll
        for (int hh = 0; hh < 2; ++hh) {
            float dt[SS];
            #pragma unroll
            for (int j2 = 0; j2 < SS; ++j2) {
                const float4 kk4 = kv4[j2*2 + hh];
                float acc =  q[hh*4+0] * kk4.x;
                acc       += q[hh*4+1] * kk4.y;
                acc       += q[hh*4+2] * kk4.z;
                acc       += q[hh*4+3] * kk4.w;
                dt[j2] = acc;
            }
            float mt[24];
            #pragma unroll
            for (int t2 = 0; t2 < 24; ++t2) mt[t2] = fmaxf(dt[t2], dt[t2+24]);
            #pragma unroll
            for (int t2 = 0; t2 < 12; ++t2) mt[t2] = fmaxf(mt[t2], mt[t2+12]);
            #pragma unroll
            for (int t2 = 0; t2 < 6; ++t2)  mt[t2] = fmaxf(mt[t2], mt[t2+6]);
            #pragma unroll
            for (int t2 = 0; t2 < 3; ++t2)  mt[t2] = fmaxf(mt[t2], mt[t2+3]);
            const float m = fmaxf(fmaxf(mt[0], mt[1]), mt[2]);
            float s = 0.f;
            #pragma unroll
            for (int j2 = 0; j2 < SS; ++j2) {
                float pv = exp2f(dt[j2] - m);
                dt[j2] = pv; s += pv;
            }
            float o0 = 0.f, o1 = 0.f, o2 = 0.f, o3 = 0.f;
            #pragma unroll
            for (int j2 = 0; j2 < SS; ++j2) {
                const float4 vv4 = kv4[KVV/4 + j2*2 + hh];
                const float pv = dt[j2];
                o0 += pv * vv4.x; o1 += pv * vv4.y;
                o2 += pv * vv4.z; o3 += pv * vv4.w;
            }
            float rs = 1.f / s;
            ov[hh*4+0] = o0*rs; ov[hh*4+1] = o1*rs;
            ov[hh*4+2] = o2*rs; ov[hh*4+3] = o3*rs;
        }
        if (lane < SS) {
            float o8[DD];
            #pragma unroll
            for (int d = 0; d < DD; ++d) {
                float acc = wb[256 + d];
                #pragma unroll
                for (int o2 = 0; o2 < HDIM; ++o2) acc += ov[o2] * wb[192 + d*8 + o2];
                o8[d] = acc;
            }
            float4* gp = reinterpret_cast<float4*>(gout + (size_t)(prob*SS + tl) * DD);
            gp[0] = make_float4(o8[0], o8[1], o8[2], o8[3]);
            gp[1] = make_float4(o8[4], o8[5], o8[6], o8[7]);
        }
    }
}

template <typename T>
__global__ void __launch_bounds__(BDIM, 1)
axial_sb(const void* xv, const void* enc_wv, const void* enc_bv,
         const void* pos_rowv, const void* pos_colv,
         const void* Wqv, const void* Wkv, const void* Wvv, const void* Wov,
         const void* bov, const void* cls_wv, const void* cls_bv,
         void* outv, void* wsv)
{
    const unsigned* xu = (const unsigned*)xv;
    int cnt = 0;
    #pragma unroll
    for (int t = 0; t < 32; ++t) {
        const unsigned w = xu[t];
        const int e = (w >> 7) & 0xff;
        cnt += (e > 100 && e < 150) ? 1 : 0;
    }
    const bool isbf = (cnt >= 20);
    constexpr bool wantbf = std::is_same<T, __hip_bfloat16>::value;
    if (isbf != wantbf) return;

    const T* x       = (const T*)xv;
    const T* enc_w   = (const T*)enc_wv;
    const T* enc_b   = (const T*)enc_bv;
    const T* pos_row = (const T*)pos_rowv;
    const T* pos_col = (const T*)pos_colv;
    const T* Wq      = (const T*)Wqv;
    const T* Wk      = (const T*)Wkv;
    const T* Wv      = (const T*)Wvv;
    const T* Wo      = (const T*)Wov;
    const T* bo      = (const T*)bov;
    const T* cls_w   = (const T*)cls_wv;
    const T* cls_b   = (const T*)cls_bv;
    T*       out     = (T*)outv;
    float*   G       = (float*)wsv;
    unsigned* flags  = (unsigned*)(G + FLAGS_OFF_SB);

    extern __shared__ float smem[];
    float* hb = smem;
    float* kv = hb + HSZ;
    float* wb = kv + KVTOT;
    float* eb = wb + 264;
    float* cb = eb + 784;

    const int bid   = blockIdx.x;
    const int batch = bid & (NBAT-1);
    const int axis  = bid >> 7;
    const int tid   = threadIdx.x;
    const int lane  = tid & 63;
    const int wav   = tid >> 6;
    const int tl    = lane < SS ? lane : SS-1;

    float* Gb   = G + (size_t)batch * GBAT;
    float* Grow = Gb;
    float* Gcol = Gb + PIX*DD;
    float* gout = axis ? Gcol : Grow;
    float* kvw  = kv + wav*KVW;

    for (int f = tid; f < 784; f += BDIM) {
        float v;
        if (f < 8)        v = l2f(enc_w[f]);
        else if (f < 16)  v = l2f(enc_b[f-8]);
        else if (f < 400) v = l2f(pos_row[f-16]);
        else              v = l2f(pos_col[f-400]);
        eb[f] = v;
    }
    __syncthreads();

    const T* xb = x + (size_t)batch * PIX;
    for (int p = tid; p < PIX; p += BDIM) {
        const int i = p / SS, j = p % SS;
        const float xv2 = l2f(xb[p]);
        #pragma unroll
        for (int d = 0; d < DD; ++d) {
            float hv = fmaxf(0.f, xv2*eb[d] + eb[8+d]) + eb[16 + i*8 + d] + eb[400 + j*8 + d];
            hb[i*RS + d*SS + j] = hv;
        }
    }

    unsigned* sibf = &flags[bid ^ NBAT];
    #pragma unroll 1
    for (int l = 0; l < NL; ++l) {
        __syncthreads();
        const int la = l*2 + axis;
        for (int f = tid; f < 264; f += BDIM) {
            float v;
            if (f < 64)       v = l2f(Wq[la*64 + f]);
            else if (f < 128) v = l2f(Wk[la*64 + f-64]);
            else if (f < 192) v = l2f(Wv[la*64 + f-128]);
            else if (f < 256) v = l2f(Wo[la*64 + f-192]);
            else              v = l2f(bo[la*8 + f-256]);
            wb[f] = v;
        }
        __syncthreads();
        if (tid == 0) flag_wait(sibf, 2u*l);
        __syncthreads();

        if (axis == 0) attn_phase_sb<0>(hb, kvw, gout, wb, wav, lane, tl);
        else           attn_phase_sb<1>(hb, kvw, gout, wb, wav, lane, tl);
        __syncthreads();

        if (tid == 0) {
            flag_post(&flags[bid], 2u*l + 1u);
            flag_wait(sibf, 2u*l + 1u);
            __threadfence();
        }
        __syncthreads();

        if (l == NL-1 && axis != 0) return;

        for (int p = tid; p < PIX; p += BDIM) {
            const int i = p / SS, j = p % SS, base = i*RS + j;
            const float4* gp = reinterpret_cast<const float4*>(Gcol + (size_t)p * DD);
            const float4 g0 = gp[0], g1 = gp[1];
            hb[base     ] = g0.x;  hb[base+  SS] = g0.y;
            hb[base+2*SS] = g0.z;  hb[base+3*SS] = g0.w;
            hb[base+4*SS] = g1.x;  hb[base+5*SS] = g1.y;
            hb[base+6*SS] = g1.z;  hb[base+7*SS] = g1.w;
        }
        __syncthreads();
        for (int p2 = tid; p2 < PIX; p2 += BDIM) {
            const int j = p2 / SS, i = p2 % SS, base = i*RS + j;
            const float4* gp = reinterpret_cast<const float4*>(Grow + (size_t)p2 * DD);
            const float4 g0 = gp[0], g1 = gp[1];
            hb[base     ] = fmaxf(0.f, hb[base     ] + g0.x);
            hb[base+  SS] = fmaxf(0.f, hb[base+  SS] + g0.y);
            hb[base+2*SS] = fmaxf(0.f, hb[base+2*SS] + g0.z);
            hb[base+3*SS] = fmaxf(0.f, hb[base+3*SS] + g0.w);
            hb[base+4*SS] = fmaxf(0.f, hb[base+4*SS] + g1.x);
            hb[base+5*SS] = fmaxf(0.f, hb[base+5*SS] + g1.y);
            hb[base+6*SS] = fmaxf(0.f, hb[base+6*SS] + g1.z);
            hb[base+7*SS] = fmaxf(0.f, hb[base+7*SS] + g1.w);
        }
        if (l < NL-1) {
            __syncthreads();
            if (tid == 0) flag_post(&flags[bid], 2u*l + 2u);
        }
    }
    __syncthreads();

    if (tid < NC) cb[tid] = l2f(cls_b[tid]);
    __syncthreads();

    float pacc[NC] = {0.f,0.f,0.f,0.f,0.f,0.f,0.f};
    for (int p = tid; p < PIX; p += BDIM) {
        const int i = p / SS, j = p % SS;
        float mv = hb[i*RS + j];
        #pragma unroll
        for (int d = 1; d < DD; ++d) mv = fmaxf(mv, hb[i*RS + d*SS + j]);
        #pragma unroll
        for (int c = 0; c < NC; ++c) pacc[c] += mv * l2f(cls_w[c*PIX + p]);
    }
    #pragma unroll
    for (int c = 0; c < NC; ++c) {
        #pragma unroll
        for (int off = 32; off > 0; off >>= 1) pacc[c] += __shfl_down(pacc[c], off, 64);
    }
    if (lane == 0) {
        #pragma unroll
        for (int c = 0; c < NC; ++c) atomicAdd(&cb[c], pacc[c]);
    }
    __syncthreads();

    if (tid < NC) {
        float m = cb[0];
        #pragma unroll
        for (int c = 1; c < NC; ++c) m = fmaxf(m, cb[c]);
        float s = 0.f;
        #pragma unroll
        for (int c = 0; c < NC; ++c) s += exp2f((cb[c]-m) * 1.44269504089f);
        const float e = exp2f((cb[tid]-m) * 1.44269504089f);
        stf(&out[batch*NC + tid], e / s);
    }
}

extern "C" void kernel_launch(void* const* d_in, const int* in_sizes, int n_in,
                              void* d_out, int out_size, void* d_ws, size_t ws_size,
                              hipStream_t stream) {
    (void)in_sizes; (void)n_in; (void)out_size;
    hipFuncSetAttribute(reinterpret_cast<const void*>(&axial_sb<float>),
                        hipFuncAttributeMaxDynamicSharedMemorySize, SMEMSB_BYTES);
    hipFuncSetAttribute(reinterpret_cast<const void*>(&axial_sb<__hip_bfloat16>),
                        hipFuncAttributeMaxDynamicSharedMemorySize, SMEMSB_BYTES);

    void* ins[12];
    for (int i = 0; i < 12; ++i) ins[i] = d_in[i];
    void* args[14];
    for (int i = 0; i < 12; ++i) args[i] = &ins[i];
    args[12] = &d_out;
    args[13] = &d_ws;

    const size_t needF = FLAGS_OFF_F*4 + 512*sizeof(unsigned);   // ~37.75 MB
    if (ws_size >= needF) {
        hipMemsetAsync((char*)d_ws + FLAGS_OFF_F*4, 0, 512*sizeof(unsigned), stream);
        int o1 = 0, o2 = 0;
        hipOccupancyMaxActiveBlocksPerMultiprocessor(
            &o1, reinterpret_cast<const void*>(&axial_f<float, 4>), BDIM, SMEMF_BYTES);
        hipOccupancyMaxActiveBlocksPerMultiprocessor(
            &o2, reinterpret_cast<const void*>(&axial_f<__hip_bfloat16, 4>), BDIM, SMEMF_BYTES);
        if (o1 >= 2 && o2 >= 2) {
            hipLaunchCooperativeKernel(reinterpret_cast<const void*>(&axial_f<float, 4>),
                                       dim3(4*NBAT), dim3(BDIM), args, (unsigned)SMEMF_BYTES, stream);
            hipLaunchCooperativeKernel(reinterpret_cast<const void*>(&axial_f<__hip_bfloat16, 4>),
                                       dim3(4*NBAT), dim3(BDIM), args, (unsigned)SMEMF_BYTES, stream);
        } else {
            hipLaunchCooperativeKernel(reinterpret_cast<const void*>(&axial_f<float, 2>),
                                       dim3(2*NBAT), dim3(BDIM), args, (unsigned)SMEMF_BYTES, stream);
            hipLaunchCooperativeKernel(reinterpret_cast<const void*>(&axial_f<__hip_bfloat16, 2>),
                                       dim3(2*NBAT), dim3(BDIM), args, (unsigned)SMEMF_BYTES, stream);
        }
    } else {
        hipMemsetAsync((char*)d_ws + FLAGS_OFF_SB*4, 0, 256*sizeof(unsigned), stream);
        hipLaunchCooperativeKernel(reinterpret_cast<const void*>(&axial_sb<float>),
                                   dim3(2*NBAT), dim3(BDIM), args, (unsigned)SMEMSB_BYTES, stream);
        hipLaunchCooperativeKernel(reinterpret_cast<const void*>(&axial_sb<__hip_bfloat16>),
                                   dim3(2*NBAT), dim3(BDIM), args, (unsigned)SMEMSB_BYTES, stream);
    }
}

// Round 6
// 1000.081 us; speedup vs baseline: 1.6578x; 1.0257x over previous
//
#include <hip/hip_runtime.h>
#include <hip/hip_bf16.h>

// R6: make the 4-way split actually launch. R5's occupancy gate depended on
// the bf16 TWIN instantiation (launched as a dead dtype-sniff no-op); its
// resource usage silently vetoed the 2-blocks/CU path -> measured occupancy
// stayed 23.9% (1 block/CU). Fix: (a) merge dtype handling into ONE kernel
// (runtime wave-uniform isbf branch in staging/classifier only; inner loops
// untouched) so there is no twin; (b) NPART=4 instantiation declares
// __launch_bounds__(512,4) (4 waves/EU = 2 blocks/CU intent; VGPR cap 128 =
// what the allocator already uses, no new spill pressure); (c) gate the 4-way
// launch on hipFuncGetAttributes.localSizeBytes==0 (spill detector, the
// R1/R3 failure mode) AND occupancy>=2; else proven NPART=2 shape (~945us).
#define BDIM 512
#define NBAT 128
#define SS   48
#define DD   8
#define HDIM 8
#define NL   8
#define NC   7
#define NWAV 8
#define PIX  (SS*SS)
#define RGN  (PIX*DD)            // one region: 18432 floats
#define GBAT (2*RGN)             // row+col regions per batch
#define BUFSZ ((size_t)NBAT*GBAT)      // one parity buffer (floats)
#define KVV  384
#define KVW  768
#define KVTOT (NWAV*KVW)
#define SMEMF_FLOATS (KVTOT + 264 + 784 + 8)
#define SMEMF_BYTES  (SMEMF_FLOATS*4)        // 28,800 B -> 2 blocks/CU LDS-wise
#define FLAGS_OFF ((size_t)2*BUFSZ)          // float offset of flags in d_ws

__device__ __forceinline__ float ldsel(const void* p, long i, bool bf) {
    return bf ? __bfloat162float(((const __hip_bfloat16*)p)[i])
              : ((const float*)p)[i];
}

__device__ __forceinline__ void flag_post(unsigned* f, unsigned v) {
    __threadfence();                                   // release: drain + L2 wb
    __hip_atomic_store(f, v, __ATOMIC_RELAXED, __HIP_MEMORY_SCOPE_AGENT);
}
__device__ __forceinline__ void flag_wait(unsigned* f, unsigned v) {
    while (__hip_atomic_load(f, __ATOMIC_RELAXED, __HIP_MEMORY_SCOPE_AGENT) < v)
        __builtin_amdgcn_s_sleep(1);
}

// Fused phase: input read straight from the exchange buffers, output straight
// to the other parity. "own" region matches this phase's orientation
// (self-written, index (prob*SS+tl): coalesced); "oth" is the opposite region
// (index (tl*SS+prob): 32B-scattered, L2-absorbed). FIRST=1: layer 0, read h0
// as-is from the own-layout copy (no relu, no add).
template <int NPROB, int FIRST>
__device__ __attribute__((noinline))
void attn_phase_f(const float4* __restrict__ gown, const float4* __restrict__ goth,
                  float4* __restrict__ gout, float* __restrict__ kvw,
                  const float* __restrict__ wb, int pbase, int wav, int lane, int tl)
{
    const float4* kv4 = reinterpret_cast<const float4*>(kvw);
    #pragma unroll 1
    for (int p = 0; p < NPROB/NWAV; ++p) {
        const int prob = pbase + wav + p*NWAV;
        const int aown = (prob*SS + tl)*2;

        float ht[DD];
        {
            const float4 o0 = gown[aown], o1 = gown[aown+1];
            if (FIRST) {
                ht[0]=o0.x; ht[1]=o0.y; ht[2]=o0.z; ht[3]=o0.w;
                ht[4]=o1.x; ht[5]=o1.y; ht[6]=o1.z; ht[7]=o1.w;
            } else {
                const int aoth = (tl*SS + prob)*2;
                const float4 t0 = goth[aoth], t1 = goth[aoth+1];
                ht[0]=fmaxf(0.f,o0.x+t0.x); ht[1]=fmaxf(0.f,o0.y+t0.y);
                ht[2]=fmaxf(0.f,o0.z+t0.z); ht[3]=fmaxf(0.f,o0.w+t0.w);
                ht[4]=fmaxf(0.f,o1.x+t1.x); ht[5]=fmaxf(0.f,o1.y+t1.y);
                ht[6]=fmaxf(0.f,o1.z+t1.z); ht[7]=fmaxf(0.f,o1.w+t1.w);
            }
        }

        // q/k/v projections; fold 0.5 (E^-0.5) * log2(e) into q for exp2.
        float q[HDIM];
        {
            float kk[HDIM], vv[HDIM];
            #pragma unroll
            for (int o = 0; o < HDIM; ++o) {
                float aq = 0.f, ak = 0.f, av = 0.f;
                #pragma unroll
                for (int d = 0; d < DD; ++d) {
                    aq += ht[d] * wb[o*8 + d];
                    ak += ht[d] * wb[64 + o*8 + d];
                    av += ht[d] * wb[128 + o*8 + d];
                }
                q[o] = aq * 0.72134752044f;  // 0.5 * log2(e)
                kk[o] = ak; vv[o] = av;
            }
            if (lane < SS) {   // lanes 48-63 would duplicate token 47: skip
                float4* kp = reinterpret_cast<float4*>(kvw + tl*8);
                kp[0] = make_float4(kk[0], kk[1], kk[2], kk[3]);
                kp[1] = make_float4(kk[4], kk[5], kk[6], kk[7]);
                float4* vp = reinterpret_cast<float4*>(kvw + KVV + tl*8);
                vp[0] = make_float4(vv[0], vv[1], vv[2], vv[3]);
                vp[1] = make_float4(vv[4], vv[5], vv[6], vv[7]);
            }
        }

        float ov[HDIM];
        #pragma unroll
        for (int hh = 0; hh < 2; ++hh) {
            float dt[SS];
            #pragma unroll
            for (int j2 = 0; j2 < SS; ++j2) {
                const float4 kk4 = kv4[j2*2 + hh];       // LDS same-addr broadcast
                float acc =  q[hh*4+0] * kk4.x;
                acc       += q[hh*4+1] * kk4.y;
                acc       += q[hh*4+2] * kk4.z;
                acc       += q[hh*4+3] * kk4.w;
                dt[j2] = acc;
            }
            // max tree (fmax exactly associative -> bitwise same as chain)
            float mt[24];
            #pragma unroll
            for (int t2 = 0; t2 < 24; ++t2) mt[t2] = fmaxf(dt[t2], dt[t2+24]);
            #pragma unroll
            for (int t2 = 0; t2 < 12; ++t2) mt[t2] = fmaxf(mt[t2], mt[t2+12]);
            #pragma unroll
            for (int t2 = 0; t2 < 6; ++t2)  mt[t2] = fmaxf(mt[t2], mt[t2+6]);
            #pragma unroll
            for (int t2 = 0; t2 < 3; ++t2)  mt[t2] = fmaxf(mt[t2], mt[t2+3]);
            const float m = fmaxf(fmaxf(mt[0], mt[1]), mt[2]);
            float s = 0.f;
            #pragma unroll
            for (int j2 = 0; j2 < SS; ++j2) {
                float pv = exp2f(dt[j2] - m);
                dt[j2] = pv; s += pv;
            }
            float o0 = 0.f, o1 = 0.f, o2 = 0.f, o3 = 0.f;
            #pragma unroll
            for (int j2 = 0; j2 < SS; ++j2) {
                const float4 vv4 = kv4[KVV/4 + j2*2 + hh];
                const float pv = dt[j2];
                o0 += pv * vv4.x;
                o1 += pv * vv4.y;
                o2 += pv * vv4.z;
                o3 += pv * vv4.w;
            }
            float rs = 1.f / s;
            ov[hh*4+0] = o0*rs; ov[hh*4+1] = o1*rs;
            ov[hh*4+2] = o2*rs; ov[hh*4+3] = o3*rs;
        }

        if (lane < SS) {
            float o8[DD];
            #pragma unroll
            for (int d = 0; d < DD; ++d) {
                float acc = wb[256 + d];
                #pragma unroll
                for (int o2 = 0; o2 < HDIM; ++o2) acc += ov[o2] * wb[192 + d*8 + o2];
                o8[d] = acc;
            }
            gout[aown]   = make_float4(o8[0], o8[1], o8[2], o8[3]);
            gout[aown+1] = make_float4(o8[4], o8[5], o8[6], o8[7]);
        }
    }
}

// NPART=4: 512 blocks (2 halves x 2 axes per batch), MINW=4 (2 blocks/CU).
// NPART=2: 256 blocks (one block per axis), MINW=1 (proven R5 shape).
template <int NPART, int MINW>
__global__ void __launch_bounds__(BDIM, MINW)
axial_u(const void* xv, const void* enc_wv, const void* enc_bv,
        const void* pos_rowv, const void* pos_colv,
        const void* Wqv, const void* Wkv, const void* Wvv, const void* Wov,
        const void* bov, const void* cls_wv, const void* cls_bv,
        void* outv, void* wsv)
{
    // dtype sniff on x (wave-uniform): low bits of each dword are a plausible
    // bf16 exponent iff data is bf16-packed; random mantissa bits if fp32.
    const unsigned* xu = (const unsigned*)xv;
    int cnt = 0;
    #pragma unroll
    for (int t = 0; t < 32; ++t) {
        const unsigned w = xu[t];
        const int e = (w >> 7) & 0xff;
        cnt += (e > 100 && e < 150) ? 1 : 0;
    }
    const bool isbf = (cnt >= 20);

    float*    G     = (float*)wsv;
    unsigned* flags = (unsigned*)(G + FLAGS_OFF);

    extern __shared__ float smem[];
    float* kv = smem;              // per-wave k/v scratch [KVTOT]
    float* wb = kv + KVTOT;        // layer weights (own axis) [264]
    float* eb = wb + 264;          // enc params [784]
    float* cb = eb + 784;          // classifier logits [8]

    const int bid   = blockIdx.x;
    const int batch = bid & (NBAT-1);
    const int part  = bid >> 7;                         // 0..NPART-1
    const int axis  = (NPART == 4) ? (part >> 1) : part;
    const int pbase = (NPART == 4) ? ((part & 1) * (SS/2)) : 0;
    constexpr int NPROB = (NPART == 4) ? (SS/2) : SS;
    const int tid   = threadIdx.x;
    const int lane  = tid & 63;
    const int wav   = tid >> 6;
    const int tl    = lane < SS ? lane : SS-1;
    float* kvw = kv + wav*KVW;

    float* b0 = G + (size_t)batch*GBAT;                 // parity-0 buffer
    float* b1 = G + BUFSZ + (size_t)batch*GBAT;         // parity-1 buffer
    float4* row0 = (float4*)b0;  float4* col0 = (float4*)(b0 + RGN);
    float4* row1 = (float4*)b1;  float4* col1 = (float4*)(b1 + RGN);

    // stage encoder/pos params
    for (int f = tid; f < 784; f += BDIM) {
        float v;
        if (f < 8)        v = ldsel(enc_wv, f, isbf);
        else if (f < 16)  v = ldsel(enc_bv, f-8, isbf);
        else if (f < 400) v = ldsel(pos_rowv, f-16, isbf);
        else              v = ldsel(pos_colv, f-400, isbf);
        eb[f] = v;
    }
    __syncthreads();

    // encoder: h0 = relu(x*enc_w + enc_b) + pos_row[i] + pos_col[j].
    // Every sibling writes the FULL image in BOTH layouts (identical values ->
    // benign race; own copy guarantees own-visibility, so no startup gate).
    for (int p = tid; p < PIX; p += BDIM) {
        const int i = p / SS, j = p % SS;
        const float xv2 = ldsel(xv, (long)batch*PIX + p, isbf);
        float hv[DD];
        #pragma unroll
        for (int d = 0; d < DD; ++d)
            hv[d] = fmaxf(0.f, xv2*eb[d] + eb[8+d]) + eb[16 + i*8 + d] + eb[400 + j*8 + d];
        const float4 a = make_float4(hv[0], hv[1], hv[2], hv[3]);
        const float4 b = make_float4(hv[4], hv[5], hv[6], hv[7]);
        col0[p*2] = a;              col0[p*2+1] = b;            // [i][j][d]
        row0[(j*SS+i)*2] = a;       row0[(j*SS+i)*2+1] = b;     // [j][i][d]
    }

    // Layer l: reads parity l&1, writes parity (l+1)&1. WV(l)=l+1 posted after
    // the phase. Gate before layer l>0: opposite-axis siblings' WV(l-1) (own
    // region is self-written; double-buffer makes WV imply read-safety).
    #pragma unroll 1
    for (int l = 0; l < NL; ++l) {
        __syncthreads();                     // prior phase wb reads / encoder done
        if (tid == 0 && l > 0) {
            if (NPART == 4) {
                const int ob = axis ? 0 : 2;
                flag_wait(&flags[batch + ob*NBAT],     (unsigned)l);
                flag_wait(&flags[batch + (ob+1)*NBAT], (unsigned)l);
            } else {
                flag_wait(&flags[batch + (1-axis)*NBAT], (unsigned)l);
            }
            __threadfence();                 // acquire: invalidate stale caches
        }
        const int la = l*2 + axis;
        for (int f = tid; f < 264; f += BDIM) {
            float v;
            if (f < 64)       v = ldsel(Wqv, la*64 + f, isbf);
            else if (f < 128) v = ldsel(Wkv, la*64 + f-64, isbf);
            else if (f < 192) v = ldsel(Wvv, la*64 + f-128, isbf);
            else if (f < 256) v = ldsel(Wov, la*64 + f-192, isbf);
            else              v = ldsel(bov, la*8 + f-256, isbf);
            wb[f] = v;
        }
        __syncthreads();                     // gate released + wb visible

        const int par = l & 1;
        float4* rin  = par ? row1 : row0;  float4* cin  = par ? col1 : col0;
        float4* rout = par ? row0 : row1;  float4* cout = par ? col0 : col1;
        const float4* own = axis ? (const float4*)cin : (const float4*)rin;
        const float4* oth = axis ? (const float4*)rin : (const float4*)cin;
        float4* gout = axis ? cout : rout;

        if (l == 0) attn_phase_f<NPROB,1>(own, oth, gout, kvw, wb, pbase, wav, lane, tl);
        else        attn_phase_f<NPROB,0>(own, oth, gout, kvw, wb, pbase, wav, lane, tl);
        __syncthreads();                     // drains each wave's global stores

        if (tid == 0) flag_post(&flags[bid], (unsigned)(l + 1));
    }

    if (part != 0) return;

    // classifier (part 0 of each batch): final h lives in parity 0 (NL even).
    if (tid == 0) {
        #pragma unroll
        for (int qp = 1; qp < NPART; ++qp)
            flag_wait(&flags[batch + qp*NBAT], (unsigned)NL);
        __threadfence();
    }
    if (tid < NC) cb[tid] = ldsel(cls_bv, tid, isbf);
    __syncthreads();

    float pacc[NC] = {0.f,0.f,0.f,0.f,0.f,0.f,0.f};
    const float* cwf = (const float*)cls_wv;
    const __hip_bfloat16* cwb = (const __hip_bfloat16*)cls_wv;
    for (int p = tid; p < PIX; p += BDIM) {
        const int i = p / SS, j = p % SS;
        const float4 c0 = col0[p*2], c1 = col0[p*2+1];
        const float4 r0 = row0[(j*SS+i)*2], r1 = row0[(j*SS+i)*2+1];
        float mv =            fmaxf(0.f, c0.x + r0.x);
        mv = fmaxf(mv,        fmaxf(0.f, c0.y + r0.y));
        mv = fmaxf(mv,        fmaxf(0.f, c0.z + r0.z));
        mv = fmaxf(mv,        fmaxf(0.f, c0.w + r0.w));
        mv = fmaxf(mv,        fmaxf(0.f, c1.x + r1.x));
        mv = fmaxf(mv,        fmaxf(0.f, c1.y + r1.y));
        mv = fmaxf(mv,        fmaxf(0.f, c1.z + r1.z));
        mv = fmaxf(mv,        fmaxf(0.f, c1.w + r1.w));
        if (isbf) {
            #pragma unroll
            for (int c = 0; c < NC; ++c) pacc[c] += mv * __bfloat162float(cwb[c*PIX + p]);
        } else {
            #pragma unroll
            for (int c = 0; c < NC; ++c) pacc[c] += mv * cwf[c*PIX + p];
        }
    }
    #pragma unroll
    for (int c = 0; c < NC; ++c) {
        #pragma unroll
        for (int off = 32; off > 0; off >>= 1) pacc[c] += __shfl_down(pacc[c], off, 64);
    }
    if (lane == 0) {
        #pragma unroll
        for (int c = 0; c < NC; ++c) atomicAdd(&cb[c], pacc[c]);
    }
    __syncthreads();

    if (tid < NC) {
        float m = cb[0];
        #pragma unroll
        for (int c = 1; c < NC; ++c) m = fmaxf(m, cb[c]);
        float s = 0.f;
        #pragma unroll
        for (int c = 0; c < NC; ++c) s += exp2f((cb[c]-m) * 1.44269504089f);
        const float e = exp2f((cb[tid]-m) * 1.44269504089f);
        const float r = e / s;
        if (isbf) ((__hip_bfloat16*)outv)[batch*NC + tid] = __float2bfloat16(r);
        else      ((float*)outv)[batch*NC + tid] = r;
    }
}

extern "C" void kernel_launch(void* const* d_in, const int* in_sizes, int n_in,
                              void* d_out, int out_size, void* d_ws, size_t ws_size,
                              hipStream_t stream) {
    (void)in_sizes; (void)n_in; (void)ws_size; (void)out_size;
    hipFuncSetAttribute(reinterpret_cast<const void*>(&axial_u<4,4>),
                        hipFuncAttributeMaxDynamicSharedMemorySize, SMEMF_BYTES);
    hipFuncSetAttribute(reinterpret_cast<const void*>(&axial_u<2,1>),
                        hipFuncAttributeMaxDynamicSharedMemorySize, SMEMF_BYTES);

    // zero epoch flags (stream-ordered, graph-capture-safe)
    hipMemsetAsync((char*)d_ws + FLAGS_OFF*4, 0, 512*sizeof(unsigned), stream);

    void* ins[12];
    for (int i = 0; i < 12; ++i) ins[i] = d_in[i];
    void* args[14];
    for (int i = 0; i < 12; ++i) args[i] = &ins[i];
    args[12] = &d_out;
    args[13] = &d_ws;     // needs 2*BUFSZ*4 + 512*4 ~= 37.75 MB (proven present in R5)

    // 4-way gate on FACTS: no spill (localSizeBytes==0, the R1/R3 failure
    // detector) and the occupancy API confirming 2 blocks/CU.
    int occ = 0;
    hipOccupancyMaxActiveBlocksPerMultiprocessor(
        &occ, reinterpret_cast<const void*>(&axial_u<4,4>), BDIM, SMEMF_BYTES);
    hipFuncAttributes fa{};
    hipFuncGetAttributes(&fa, reinterpret_cast<const void*>(&axial_u<4,4>));

    if (occ >= 2 && fa.localSizeBytes == 0) {
        hipLaunchCooperativeKernel(reinterpret_cast<const void*>(&axial_u<4,4>),
                                   dim3(4*NBAT), dim3(BDIM), args, (unsigned)SMEMF_BYTES, stream);
    } else {
        hipLaunchCooperativeKernel(reinterpret_cast<const void*>(&axial_u<2,1>),
                                   dim3(2*NBAT), dim3(BDIM), args, (unsigned)SMEMF_BYTES, stream);
    }
}